// Round 6
// baseline (69.862 us; speedup 1.0000x reference)
//
#include <hip/hip_runtime.h>
#include <math.h>

// HippoSSKernel (S4 SSKernelDiag forward, ZOH): K[h,l] = 2*Re(sum_n Cw[h,n]*exp(dtA[h,n]*l))
// H=1024, N=64, CH=1, L=2048.
//
// R6 = R5 + INSTRUMENTATION: main loop repeated REPS=6 times (reps 0..4 kept
// live via asm, then re-zeroed; rep 5 produces the exact R5 output). Purpose:
// (a) marginal main-loop cost = (dur_R6 - dur_R5)/5, (b) dur > 40us pushes our
// kernel into rocprof top-5 so VALUBusy/Occupancy/VGPR/bank-conflict rows
// become visible for the real inner loop.

#define HH   1024
#define NN   64
#define LLEN 2048
#define TPB  256
#define HPB  2                 // heads per block
#define TPH  (TPB / HPB)       // 128 threads per head
#define LPT  (LLEN / TPH)      // 16 terms per thread
#define REPS 6

__device__ __forceinline__ float2 cmul(float2 a, float2 b) {
    return make_float2(fmaf(a.x, b.x, -(a.y * b.y)),
                       fmaf(a.x, b.y,   a.y * b.x));
}

__global__ __launch_bounds__(TPB, 2) void sskernel_diag(
    const float* __restrict__ log_dt,      // (H,)
    const float* __restrict__ log_w_real,  // (H,N)
    const float* __restrict__ w_imag,      // (H,N)
    const float* __restrict__ C_re,        // (1,H,N)
    const float* __restrict__ C_im,        // (1,H,N)
    float* __restrict__ out)               // (1,H,L)
{
    __shared__ float2 s_T[HPB][NN][NN + 1];  // [s][n][j] = b_n^j (padded rows)
    __shared__ float4 s_P[HPB][2][NN];       // [s][w2][n] = (hw.x, hw.y, q.x, q.y)

    const int t    = threadIdx.x;
    const int s    = t >> 7;               // head within block (0,1)
    const int tt   = t & (TPH - 1);        // thread within head (0..127)
    const int lane = t & 63;
    const int w2   = (t >> 6) & 1;         // wave within head (0,1)
    const int h    = blockIdx.x * HPB + s;

    // ---- Prologue: thread (h, w2, lane) computes n = lane's parameters ----
    const int n   = lane;
    const int idx = h * NN + n;
    const float dtv = expf(log_dt[h]);
    const float wr  = -expf(log_w_real[idx]);
    const float wi  = w_imag[idx];
    const float dar = wr * dtv;
    const float dai = wi * dtv;

    const float em = expf(dar);
    float sv, cv;
    sincosf(dai, &sv, &cv);
    const float2 b = make_float2(em * cv, em * sv);     // exp(dtA)

    // Cw2 = 2 * C * (b - 1) / w   (final factor of 2 folded in)
    const float numr = b.x - 1.0f;
    const float numi = b.y;
    const float inv  = 2.0f / (wr * wr + wi * wi);
    const float tr = (numr * wr + numi * wi) * inv;
    const float ti = (numi * wr - numr * wi) * inv;
    const float cr = C_re[idx];
    const float ci = C_im[idx];
    const float2 Cw2 = make_float2(cr * tr - ci * ti, cr * ti + ci * tr);

    // squaring chain p[k] = b^(2^k) up to q = b^128
    const float2 p1 = cmul(b,  b);
    const float2 p2 = cmul(p1, p1);
    const float2 p3 = cmul(p2, p2);
    const float2 p4 = cmul(p3, p3);   // b^16
    const float2 p5 = cmul(p4, p4);   // b^32
    const float2 p6 = cmul(p5, p5);   // b^64
    const float2 p7 = cmul(p6, p6);   // q = b^128

    // hw = Cw2 * b^(64*w2); packed per-n constant (hw, q)
    float2 hw = Cw2;
    if (w2) hw = cmul(hw, p6);
    s_P[s][w2][n] = make_float4(hw.x, hw.y, p7.x, p7.y);

    // fill T[n][32*w2 .. 32*w2+31] = b^j incrementally from b^(32*w2)
    float2 e = make_float2(1.0f, 0.0f);
    if (w2) e = p5;
#pragma unroll
    for (int j2 = 0; j2 < 32; ++j2) {
        s_T[s][n][32 * w2 + j2] = e;
        e = cmul(e, b);
    }
    __syncthreads();

    // ---- Main loop (x REPS for instrumentation) ----
    float acc[LPT];
#pragma unroll
    for (int j = 0; j < LPT; ++j) acc[j] = 0.0f;

#pragma unroll 1
    for (int rep = 0; rep < REPS; ++rep) {
        asm volatile("" ::: "memory");   // no cross-rep CSE/hoist of LDS reads

#pragma unroll 8
        for (int nn = 0; nn < NN; ++nn) {
            const float2 lo = s_T[s][nn][lane];   // b_nn^lane
            const float4 P  = s_P[s][w2][nn];     // uniform -> broadcast

            const float zx = fmaf(P.x, lo.x, -(P.y * lo.y));  // Re(hw*lo)
            const float zy = fmaf(P.x, lo.y,   P.y * lo.x);   // Im(hw*lo)
            float u0 = zx;
            float u1 = fmaf(zx, P.z, -(zy * P.w));            // Re(hw*lo*q)
            const float an = P.z + P.z;                        // 2 Re(q)
            const float m  = fmaf(P.z, P.z, P.w * P.w);        // |q|^2
            acc[0] += u0;
            acc[1] += u1;
#pragma unroll
            for (int j = 2; j < LPT; ++j) {
                const float u = fmaf(an, u1, -(m * u0));      // Chebyshev step
                acc[j] += u;
                u0 = u1;
                u1 = u;
            }
        }

        if (rep != REPS - 1) {
            // keep reps 0..REPS-2 alive (anti-DCE), then reset for next rep
#pragma unroll
            for (int j = 0; j < LPT; ++j) {
                asm volatile("" : "+v"(acc[j]));
                acc[j] = 0.0f;
            }
        }
    }

    // ---- Epilogue: coalesced stores (2x folded into Cw2) ----
    float* o = out + (size_t)h * LLEN;
#pragma unroll
    for (int j = 0; j < LPT; ++j)
        o[tt + j * TPH] = acc[j];
}

extern "C" void kernel_launch(void* const* d_in, const int* in_sizes, int n_in,
                              void* d_out, int out_size, void* d_ws, size_t ws_size,
                              hipStream_t stream) {
    const float* log_dt     = (const float*)d_in[0];
    const float* log_w_real = (const float*)d_in[1];
    const float* w_imag     = (const float*)d_in[2];
    const float* C_re       = (const float*)d_in[3];
    const float* C_im       = (const float*)d_in[4];
    float* out = (float*)d_out;

    sskernel_diag<<<HH / HPB, TPB, 0, stream>>>(log_dt, log_w_real, w_imag, C_re, C_im, out);
}

// Round 7
// 16.284 us; speedup vs baseline: 4.2901x; 4.2901x over previous
//
#include <hip/hip_runtime.h>
#include <math.h>

// HippoSSKernel (S4 SSKernelDiag forward, ZOH): K[h,l] = 2*Re(sum_n Cw[h,n]*exp(dtA[h,n]*l))
// H=1024, N=64, CH=1, L=2048.
//
// R7 = R5 restructured for PACKED FP32 (v_pk_fma_f32 etc., VOP3P): each packed
// float2 holds values for an (even n, odd n) PAIR. The Chebyshev recurrence
// u_{j+1} = 2Re(q) u_j - |q|^2 u_{j-1} is elementwise -> packs perfectly.
// Per n-pair: 3 LDS reads (1 table b128 + 2 broadcast b128) + 53 pk-inst for
// 32 terms, i.e. half the scalar instruction count of R5. Main loop was at
// ~85% of the measured 103 TF scalar-VALU ceiling (R6 instrumentation:
// marginal loop cost 10.08us, fixed overhead ~9.4us) -> only lever is fewer
// instructions.

#define HH   1024
#define NN   64
#define LLEN 2048
#define TPB  256
#define HPB  2                 // heads per block
#define TPH  (TPB / HPB)       // 128 threads per head
#define LPT  (LLEN / TPH)      // 16 terms per thread
#define NP   (NN / 2)          // 32 n-pairs

typedef float v2f __attribute__((ext_vector_type(2)));
typedef float v4f __attribute__((ext_vector_type(4)));

__device__ __forceinline__ float2 cmul(float2 a, float2 b) {
    return make_float2(fmaf(a.x, b.x, -(a.y * b.y)),
                       fmaf(a.x, b.y,   a.y * b.x));
}

__device__ __forceinline__ v2f vfma(v2f a, v2f b, v2f c) {
    return __builtin_elementwise_fma(a, b, c);
}

__global__ __launch_bounds__(TPB, 2) void sskernel_diag(
    const float* __restrict__ log_dt,      // (H,)
    const float* __restrict__ log_w_real,  // (H,N)
    const float* __restrict__ w_imag,      // (H,N)
    const float* __restrict__ C_re,        // (1,H,N)
    const float* __restrict__ C_im,        // (1,H,N)
    float* __restrict__ out)               // (1,H,L)
{
    // [s][p][j] = {x_even, x_odd, y_even, y_odd} of b^j for pair p=(2p,2p+1)
    __shared__ v4f s_T2[HPB][NP][NN + 1];     // padded rows: 2*32*65*16 = 66560 B
    __shared__ v4f s_HW[HPB][2][NP];          // {hwx_e, hwx_o, hwy_e, hwy_o}
    __shared__ v4f s_Q[HPB][NP];              // {qx_e, qx_o, qy_e, qy_o}

    const int t    = threadIdx.x;
    const int s    = t >> 7;               // head within block (0,1)
    const int tt   = t & (TPH - 1);        // thread within head (0..127)
    const int lane = t & 63;
    const int w2   = (t >> 6) & 1;         // wave within head (0,1)
    const int h    = blockIdx.x * HPB + s;

    // ---- Prologue: thread (h, w2, lane) computes n = lane's parameters ----
    const int n   = lane;
    const int p   = n >> 1;
    const int sl  = n & 1;                 // slot within pair
    const int idx = h * NN + n;
    const float dtv = expf(log_dt[h]);
    const float wr  = -expf(log_w_real[idx]);
    const float wi  = w_imag[idx];
    const float dar = wr * dtv;
    const float dai = wi * dtv;

    const float em = expf(dar);
    float sv, cv;
    sincosf(dai, &sv, &cv);
    const float2 b = make_float2(em * cv, em * sv);     // exp(dtA)

    // Cw2 = 2 * C * (b - 1) / w   (final factor of 2 folded in)
    const float numr = b.x - 1.0f;
    const float numi = b.y;
    const float inv  = 2.0f / (wr * wr + wi * wi);
    const float tr = (numr * wr + numi * wi) * inv;
    const float ti = (numi * wr - numr * wi) * inv;
    const float cr = C_re[idx];
    const float ci = C_im[idx];
    const float2 Cw2 = make_float2(cr * tr - ci * ti, cr * ti + ci * tr);

    // squaring chain p[k] = b^(2^k) up to q = b^128
    const float2 q1 = cmul(b,  b);
    const float2 q2 = cmul(q1, q1);
    const float2 q3 = cmul(q2, q2);
    const float2 q4 = cmul(q3, q3);   // b^16
    const float2 q5 = cmul(q4, q4);   // b^32
    const float2 q6 = cmul(q5, q5);   // b^64
    const float2 q7 = cmul(q6, q6);   // q = b^128

    // hw = Cw2 * b^(64*w2); write packed slots
    float2 hw = Cw2;
    if (w2) hw = cmul(hw, q6);
    {
        float* f = (float*)&s_HW[s][w2][p];
        f[sl] = hw.x; f[2 + sl] = hw.y;
    }
    if (w2 == 0) {
        float* f = (float*)&s_Q[s][p];
        f[sl] = q7.x; f[2 + sl] = q7.y;
    }

    // fill T2[p][32*w2 .. 32*w2+31] slots for this n, from b^(32*w2)
    float2 e = make_float2(1.0f, 0.0f);
    if (w2) e = q5;
#pragma unroll
    for (int j2 = 0; j2 < 32; ++j2) {
        float* f = (float*)&s_T2[s][p][32 * w2 + j2];
        f[sl] = e.x; f[2 + sl] = e.y;
        e = cmul(e, b);
    }
    __syncthreads();

    // ---- Main loop: 3 LDS reads + 53 pk-inst per n-pair (32 terms) ----
    v2f acc[LPT] = {};

#pragma unroll 8
    for (int pp = 0; pp < NP; ++pp) {
        const v4f T  = s_T2[s][pp][lane];    // one ds_read_b128, conflict-free
        const v4f HW = s_HW[s][w2][pp];      // uniform -> broadcast
        const v4f Q  = s_Q[s][pp];           // uniform -> broadcast

        const v2f lox = {T.x, T.y},  loy = {T.z, T.w};
        const v2f hwx = {HW.x, HW.y}, hwy = {HW.z, HW.w};
        const v2f qx  = {Q.x, Q.y},  qy  = {Q.z, Q.w};

        const v2f an = qx + qx;                       // 2 Re(q)
        const v2f m  = vfma(qx, qx, qy * qy);         // |q|^2
        const v2f zx = vfma(hwx, lox, -(hwy * loy));  // Re(hw*lo)
        const v2f zy = vfma(hwx, loy, hwy * lox);     // Im(hw*lo)
        v2f u0 = zx;
        v2f u1 = vfma(zx, qx, -(zy * qy));            // Re(hw*lo*q)
        acc[0] += u0;
        acc[1] += u1;
#pragma unroll
        for (int j = 2; j < LPT; ++j) {
            const v2f u = vfma(an, u1, -(m * u0));    // packed Chebyshev step
            acc[j] += u;
            u0 = u1;
            u1 = u;
        }
    }

    // ---- Epilogue: horizontal add of even/odd-n partials, coalesced stores ----
    float* o = out + (size_t)h * LLEN;
#pragma unroll
    for (int j = 0; j < LPT; ++j)
        o[tt + j * TPH] = acc[j].x + acc[j].y;
}

extern "C" void kernel_launch(void* const* d_in, const int* in_sizes, int n_in,
                              void* d_out, int out_size, void* d_ws, size_t ws_size,
                              hipStream_t stream) {
    const float* log_dt     = (const float*)d_in[0];
    const float* log_w_real = (const float*)d_in[1];
    const float* w_imag     = (const float*)d_in[2];
    const float* C_re       = (const float*)d_in[3];
    const float* C_im       = (const float*)d_in[4];
    float* out = (float*)d_out;

    sskernel_diag<<<HH / HPB, TPB, 0, stream>>>(log_dt, log_w_real, w_imag, C_re, C_im, out);
}